// Round 13
// baseline (276.088 us; speedup 1.0000x reference)
//
#include <hip/hip_runtime.h>

// Locally connected layer:
// out[b,o,h,w] = sum_{c,i,j} x[b,c,h+i,w+j] * W[o,c,h,w,i,j] + bias[o,h,w]
// x: [32,32,64,64] f32, W: [64,32,62,62,3,3] f32, bias: [64,62,62] f32
// out: [32,64,62,62] f32
//
// R13: kill the L1-thrash wall. R12 analysis: each wave redundantly re-loaded
// the same 24 KB x slab every channel; per-CU L1 working set ~58 KB/channel
// thrashed the 32 KB L1; L1 miss-queue throughput was the per-CU serializer
// (insensitive to occupancy, VALUBusy 27%).
//  - x: staged ONCE per 4-wave block per channel into LDS via 6 coalesced
//    global_load_lds dwordx4 per wave (R6-validated goff scheme), dbuf.
//  - W: staged coalesced per wave via 9 global_load_lds dword (R10-validated,
//    the 421->242 win), dbuf.
//  - Readback: x = 24 ds_read_b128 + DPP 0x101 halo (R8-validated);
//    W = 9 ds_read_b128 (144-B lane stride = 2-way alias, free).
//  - T3-minimal 2-phase: issue STAGE(c+1), compute(c) from LDS, ONE
//    __syncthreads (vmcnt drain) per channel. Stage latency (~900 cy HBM for
//    W) hides under ~2000 cy compute.
//  - LDS 67.6 KB -> 2 blocks/CU. Plain __launch_bounds__(256) (min-waves
//    clause spilled in R4/R8 - never again). Chunked XCD swizzle (R3).

#define C_  32
#define B_  32
#define O_  64
#define H_  64
#define W_  64
#define OH_ 62
#define OW_ 62

typedef float vfloat2 __attribute__((ext_vector_type(2)));
typedef float vfloat4 __attribute__((ext_vector_type(4)));

#define GLL16(gaddr, laddr)                                                     \
    __builtin_amdgcn_global_load_lds(                                           \
        (const __attribute__((address_space(1))) void*)(gaddr),                 \
        (__attribute__((address_space(3))) void*)(laddr), 16, 0, 0)

#define GLL4(gaddr, laddr)                                                      \
    __builtin_amdgcn_global_load_lds(                                           \
        (const __attribute__((address_space(1))) void*)(gaddr),                 \
        (__attribute__((address_space(3))) void*)(laddr), 4, 0, 0)

// dst[lane] = src[lane+1] within each 16-lane row (validated R8)
__device__ __forceinline__ float dpp_nextlane(float v) {
    return __int_as_float(__builtin_amdgcn_update_dpp(
        0, __float_as_int(v), 0x101, 0xf, 0xf, true));
}

__global__ __launch_bounds__(256)
void lcl_kernel(const float* __restrict__ x,
                const float* __restrict__ Wt,
                const float* __restrict__ bias,
                float* __restrict__ out) {
    // x slab per channel: [batch 32][row 3][col 64] f32 = 24576 B, dbuf.
    // W row per wave: 2232 B used, 2304 B padded, dbuf. Total 67584 B.
    __shared__ float ldsX[2][6144];
    __shared__ float ldsW[2][4][576];

    // ---- chunked XCD swizzle (hw: XCD = blockIdx.x % 8)
    const int nblk    = (O_ / 4) * OH_;              // 992 = 8 * 124
    const int i0      = blockIdx.x;
    const int logical = (i0 & 7) * (nblk >> 3) + (i0 >> 3);
    const int og      = logical & 15;                // o-group (fast)
    const int h       = logical >> 4;                // 0..61

    const int wv_i = threadIdx.x >> 6;               // wave 0..3
    const int o    = (og << 2) + wv_i;
    const int lane = threadIdx.x & 63;
    const int wg   = lane & 15;                      // w0 = 4*wg
    const int bg   = lane >> 4;                      // b0 = 8*bg
    const int w0   = wg * 4;
    const int b0   = bg * 8;
    const bool full = (wg < 15);                     // wg15 stores only w=60,61

    float acc[8][4];
#pragma unroll
    for (int bi = 0; bi < 8; ++bi)
#pragma unroll
        for (int wi = 0; wi < 4; ++wi) acc[bi][wi] = 0.f;

    // ---- per-lane global x source offsets for the 6 gll16 (const over c)
    // slab byte S -> batch = S/768, within = S%768;
    // global byte = batch*524288 + h*256 + within (+ c*16384 per call)
    unsigned goff[6];
#pragma unroll
    for (int k = 0; k < 6; ++k) {
        unsigned S      = (unsigned)wv_i * 6144u + (unsigned)k * 1024u + (unsigned)lane * 16u;
        unsigned batch  = ((S >> 8) * 171u) >> 9;    // /768 for S<24576
        unsigned within = S - batch * 768u;
        goff[k] = batch * 524288u + (unsigned)h * 256u + within;
    }

    // W row base (floats): o*C*34596 + h*558 (+ c*34596 per channel)
    const long wrowbase = (long)o * (C_ * 34596) + (long)h * 558;

#define STAGE_X(buf, cidx) do {                                                 \
        const char* xb_ = (const char*)x + (unsigned)(cidx) * 16384u;           \
        char* lb_ = (char*)&ldsX[buf][0] + wv_i * 6144;                         \
        _Pragma("unroll")                                                       \
        for (int k_ = 0; k_ < 6; ++k_)                                          \
            GLL16(xb_ + goff[k_], lb_ + k_ * 1024);                             \
    } while (0)

    // stage one 2232-B W row coalesced (9 gll dword; tail covers [1976,2232))
#define STAGE_W(buf, cidx) do {                                                 \
        const char* src_ = (const char*)(Wt + wrowbase + (long)(cidx) * 34596); \
        char* dst_ = (char*)&ldsW[buf][wv_i][0];                                \
        _Pragma("unroll")                                                       \
        for (int k_ = 0; k_ < 8; ++k_)                                          \
            GLL4(src_ + k_ * 256 + lane * 4, dst_ + k_ * 256);                  \
        GLL4(src_ + 1976 + lane * 4, dst_ + 1976);                              \
    } while (0)

    // lane's 36 W floats (9 x ds_read_b128; 144-B lane stride = 2-way alias,
    // 4-way broadcast across bg). wg=15 tail floats are pad garbage -> only
    // feed acc[..][2/3], never stored for that lane.
#define DSREAD_W(buf) do {                                                      \
        const char* wrow_ = (const char*)&ldsW[buf][wv_i][0] + wg * 144;        \
        _Pragma("unroll")                                                       \
        for (int q_ = 0; q_ < 9; ++q_)                                          \
            wq[q_] = *reinterpret_cast<const vfloat4*>(wrow_ + q_ * 16);        \
    } while (0)

#define WQ(t) (wq[(t) >> 2][(t) & 3])

    // per bi: 3 ds_read_b128 + DPP halo + 36 FMAs
#define COMPUTE(buf) do {                                                       \
        const char* bb_ = (const char*)&ldsX[buf][0] + b0 * 768 + wg * 16;      \
        _Pragma("unroll")                                                       \
        for (int bi_ = 0; bi_ < 8; ++bi_) {                                     \
            float4 v4_[3];                                                      \
            _Pragma("unroll")                                                   \
            for (int r_ = 0; r_ < 3; ++r_)                                      \
                v4_[r_] = *reinterpret_cast<const float4*>(                     \
                    bb_ + bi_ * 768 + r_ * 256);                                \
            float xr_[3][6];                                                    \
            _Pragma("unroll")                                                   \
            for (int r_ = 0; r_ < 3; ++r_) {                                    \
                xr_[r_][0] = v4_[r_].x; xr_[r_][1] = v4_[r_].y;                 \
                xr_[r_][2] = v4_[r_].z; xr_[r_][3] = v4_[r_].w;                 \
                xr_[r_][4] = dpp_nextlane(v4_[r_].x);                           \
                xr_[r_][5] = dpp_nextlane(v4_[r_].y);                           \
            }                                                                   \
            _Pragma("unroll")                                                   \
            for (int wi_ = 0; wi_ < 4; ++wi_)                                   \
            _Pragma("unroll")                                                   \
            for (int ii_ = 0; ii_ < 3; ++ii_)                                   \
            _Pragma("unroll")                                                   \
            for (int j_ = 0; j_ < 3; ++j_)                                      \
                acc[bi_][wi_] = fmaf(xr_[ii_][wi_ + j_],                        \
                                     WQ(wi_ * 9 + ii_ * 3 + j_),                \
                                     acc[bi_][wi_]);                            \
        }                                                                       \
    } while (0)

    vfloat4 wq[9];

    // ---- prologue: stage c=0, drain, then pipeline
    STAGE_X(0, 0);
    STAGE_W(0, 0);
    __syncthreads();

    for (int c = 0; c < C_; ++c) {
        const int p = c & 1;
        if (c + 1 < C_) {                // issue next-channel stage FIRST
            STAGE_X(p ^ 1, c + 1);
            STAGE_W(p ^ 1, c + 1);
        }
        DSREAD_W(p);
        COMPUTE(p);
        __syncthreads();                 // one vmcnt/lgkm drain per channel
    }

    // ---- epilogue: bias + nontemporal float2 stores (8B-aligned)
    const float* brow = bias + ((long)o * OH_ + h) * OW_ + w0;
    float2 bv0 = *reinterpret_cast<const float2*>(brow);
    float2 bv1;
    if (full) bv1 = *reinterpret_cast<const float2*>(brow + 2);
    else { bv1.x = 0.f; bv1.y = 0.f; }

#pragma unroll
    for (int bi = 0; bi < 8; ++bi) {
        float* orow = out + (((long)(b0 + bi) * O_ + o) * OH_ + h) * OW_ + w0;
        vfloat2 s0; s0.x = acc[bi][0] + bv0.x; s0.y = acc[bi][1] + bv0.y;
        __builtin_nontemporal_store(s0, reinterpret_cast<vfloat2*>(orow));
        if (full) {
            vfloat2 s1; s1.x = acc[bi][2] + bv1.x; s1.y = acc[bi][3] + bv1.y;
            __builtin_nontemporal_store(s1, reinterpret_cast<vfloat2*>(orow) + 1);
        }
    }

#undef STAGE_X
#undef STAGE_W
#undef DSREAD_W
#undef WQ
#undef COMPUTE
}

extern "C" void kernel_launch(void* const* d_in, const int* in_sizes, int n_in,
                              void* d_out, int out_size, void* d_ws, size_t ws_size,
                              hipStream_t stream) {
    const float* x    = (const float*)d_in[0];
    const float* Wt   = (const float*)d_in[1];
    const float* bias = (const float*)d_in[2];
    float* out        = (float*)d_out;

    dim3 grid((O_ / 4) * OH_);   // 992 blocks, XCD-swizzled in-kernel
    dim3 block(256);
    lcl_kernel<<<grid, block, 0, stream>>>(x, Wt, bias, out);
}

// Round 14
// 160.271 us; speedup vs baseline: 1.7226x; 1.7226x over previous
//
#include <hip/hip_runtime.h>

// Locally connected layer:
// out[b,o,h,w] = sum_{c,i,j} x[b,c,h+i,w+j] * W[o,c,h,w,i,j] + bias[o,h,w]
// x: [32,32,64,64] f32, W: [64,32,62,62,3,3] f32, bias: [64,62,62] f32
// out: [32,64,62,62] f32
//
// R14: 2 o's per wave (halves x traffic per FMA, doubles FMA per wave to
// ~1152 cy/channel), barrier-free (R12 structure; R13's barriered staging
// regressed). W: per-wave coalesced gll->LDS rows for o and o+1, DEPTH-3
// prefetch over 4 buffers -> top-of-loop vmcnt(36) only waits on a gll
// issued >=2 channels ago (FIFO-clean; R11 lesson). x: direct float4 loads,
// 3-slot rotation interleaved with FMAs; STAGE_W(c+3) issued youngest.
// 256-thread blocks (the 64-thread heuristic gave VGPR=64 in R12, killing
// ILP). Plain launch_bounds (min-waves clause spills: R4/R8). DPP halo
// 0x101 (R8-validated), chunked XCD swizzle (R3-validated).

#define C_  32
#define B_  32
#define O_  64
#define H_  64
#define W_  64
#define OH_ 62
#define OW_ 62

typedef float vfloat2 __attribute__((ext_vector_type(2)));
typedef float vfloat4 __attribute__((ext_vector_type(4)));

#define GLL4(gaddr, laddr)                                                      \
    __builtin_amdgcn_global_load_lds(                                           \
        (const __attribute__((address_space(1))) void*)(gaddr),                 \
        (__attribute__((address_space(3))) void*)(laddr), 4, 0, 0)

// dst[lane] = src[lane+1] within each 16-lane row (validated R8)
__device__ __forceinline__ float dpp_nextlane(float v) {
    return __int_as_float(__builtin_amdgcn_update_dpp(
        0, __float_as_int(v), 0x101, 0xf, 0xf, true));
}

#define WAITV(n) do {                                                           \
        asm volatile("s_waitcnt vmcnt(" #n ")" ::: "memory");                   \
        __builtin_amdgcn_sched_barrier(0);                                      \
    } while (0)

__global__ __launch_bounds__(256)
void lcl_kernel(const float* __restrict__ x,
                const float* __restrict__ Wt,
                const float* __restrict__ bias,
                float* __restrict__ out) {
    // W rows: [4 buffers][4 waves][2 o's][576 floats] = 73728 B
    __shared__ float ldsW[4][4][2][576];

    // ---- chunked XCD swizzle (hw: XCD = blockIdx.x % 8); 496 = 8 * 62
    const int i0      = blockIdx.x;
    const int logical = (i0 & 7) * 62 + (i0 >> 3);
    const int og      = logical & 7;                 // o-octet (fast)
    const int h       = logical >> 3;                // 0..61

    const int wv_i = threadIdx.x >> 6;               // wave 0..3
    const int o0   = (og << 3) + (wv_i << 1);        // this wave: o0, o0+1
    const int lane = threadIdx.x & 63;
    const int wg   = lane & 15;                      // w0 = 4*wg
    const int bg   = lane >> 4;                      // b0 = 8*bg
    const int w0   = wg * 4;
    const int b0   = bg * 8;
    const bool full = (wg < 15);                     // wg15 stores only w=60,61

    float acc0[8][4], acc1[8][4];
#pragma unroll
    for (int bi = 0; bi < 8; ++bi)
#pragma unroll
        for (int wi = 0; wi < 4; ++wi) { acc0[bi][wi] = 0.f; acc1[bi][wi] = 0.f; }

    // W row bases (floats): o*C*34596 + h*558
    const long wrow0 = (long)o0 * (C_ * 34596) + (long)h * 558;
    const long wrow1 = wrow0 + (long)C_ * 34596;     // o0+1

    // x byte base for (b0, h, w0)
    const char* xb0 = (const char*)x + (unsigned)b0 * 524288u
                      + (unsigned)h * 256u + (unsigned)wg * 16u;

    // stage both 2232-B W rows coalesced (2 x 9 gll dword; tail instr covers
    // [1976,2232), overlap [1976,2048) double-written with same data).
#define STAGE_W2(buf, cidx) do {                                                \
        const char* s0_ = (const char*)(Wt + wrow0 + (long)(cidx) * 34596);     \
        const char* s1_ = (const char*)(Wt + wrow1 + (long)(cidx) * 34596);     \
        char* d0_ = (char*)&ldsW[buf][wv_i][0][0];                              \
        char* d1_ = (char*)&ldsW[buf][wv_i][1][0];                              \
        _Pragma("unroll")                                                       \
        for (int k_ = 0; k_ < 8; ++k_)                                          \
            GLL4(s0_ + k_ * 256 + lane * 4, d0_ + k_ * 256);                    \
        GLL4(s0_ + 1976 + lane * 4, d0_ + 1976);                                \
        _Pragma("unroll")                                                       \
        for (int k_ = 0; k_ < 8; ++k_)                                          \
            GLL4(s1_ + k_ * 256 + lane * 4, d1_ + k_ * 256);                    \
        GLL4(s1_ + 1976 + lane * 4, d1_ + 1976);                                \
    } while (0)

    // lane's 36 W floats per o (9 ds_read_b128, 144-B lane stride = 2-way
    // alias = free). wg=15 tail reads pad garbage, never stored.
#define DSREAD_W2(buf) do {                                                     \
        const char* r0_ = (const char*)&ldsW[buf][wv_i][0][0] + wg * 144;       \
        const char* r1_ = (const char*)&ldsW[buf][wv_i][1][0] + wg * 144;       \
        _Pragma("unroll")                                                       \
        for (int q_ = 0; q_ < 9; ++q_) {                                        \
            wq0[q_] = *reinterpret_cast<const vfloat4*>(r0_ + q_ * 16);         \
            wq1[q_] = *reinterpret_cast<const vfloat4*>(r1_ + q_ * 16);         \
        }                                                                       \
    } while (0)

#define WQ0(t) (wq0[(t) >> 2][(t) & 3])
#define WQ1(t) (wq1[(t) >> 2][(t) & 3])

    // issue 3 float4 rows of batch b0+bi_ for channel cidx into slot s_
#define XLD(s_, cidx, bi_) do {                                                 \
        const char* p_ = xb0 + (unsigned)(bi_) * 524288u                        \
                         + (unsigned)(cidx) * 16384u;                           \
        xv##s_[0] = *reinterpret_cast<const float4*>(p_);                       \
        xv##s_[1] = *reinterpret_cast<const float4*>(p_ + 256);                 \
        xv##s_[2] = *reinterpret_cast<const float4*>(p_ + 512);                 \
    } while (0)

    // expand slot s_ via DPP halo, 36 FMAs into acc0[bi_] + 36 into acc1[bi_]
#define FMA2(s_, bi_) do {                                                      \
        float xr_[3][6];                                                        \
        _Pragma("unroll")                                                       \
        for (int r_ = 0; r_ < 3; ++r_) {                                        \
            xr_[r_][0] = xv##s_[r_].x; xr_[r_][1] = xv##s_[r_].y;               \
            xr_[r_][2] = xv##s_[r_].z; xr_[r_][3] = xv##s_[r_].w;               \
            xr_[r_][4] = dpp_nextlane(xv##s_[r_].x);                            \
            xr_[r_][5] = dpp_nextlane(xv##s_[r_].y);                            \
        }                                                                       \
        _Pragma("unroll")                                                       \
        for (int wi_ = 0; wi_ < 4; ++wi_)                                       \
        _Pragma("unroll")                                                       \
        for (int ii_ = 0; ii_ < 3; ++ii_)                                       \
        _Pragma("unroll")                                                       \
        for (int j_ = 0; j_ < 3; ++j_) {                                        \
            acc0[bi_][wi_] = fmaf(xr_[ii_][wi_ + j_],                           \
                                  WQ0(wi_ * 9 + ii_ * 3 + j_), acc0[bi_][wi_]); \
            acc1[bi_][wi_] = fmaf(xr_[ii_][wi_ + j_],                           \
                                  WQ1(wi_ * 9 + ii_ * 3 + j_), acc1[bi_][wi_]); \
        }                                                                       \
    } while (0)

    vfloat4 wq0[9], wq1[9];
    float4  xvA[3], xvB[3], xvC[3];

    // ---- prologue: depth-3 W prefetch (54 gll outstanding)
    STAGE_W2(0, 0);
    STAGE_W2(1, 1);
    STAGE_W2(2, 2);

    for (int c = 0; c < C_; ++c) {
        // gll(c) landed iff <= 36 outstanding (gll(c+1), gll(c+2) may remain;
        // both were issued >= 1 channel ago; x of c-1 all consumed/retired).
        WAITV(36);
        DSREAD_W2(c & 3);                 // 18 ds_read_b128 (compiler lgkm)
        XLD(A, c, 0);
        XLD(B, c, 1);
        __builtin_amdgcn_sched_barrier(0);
        XLD(C, c, 2); FMA2(A, 0);
        XLD(A, c, 3); FMA2(B, 1);
        XLD(B, c, 4); FMA2(C, 2);
        XLD(C, c, 5); FMA2(A, 3);
        XLD(A, c, 6); FMA2(B, 4);
        XLD(B, c, 7); FMA2(C, 5);
        __builtin_amdgcn_sched_barrier(0);
        {                                 // stage W(c+3): YOUNGEST VMEM
            const int cn = (c + 3 < C_) ? (c + 3) : (C_ - 1);
            STAGE_W2((c + 3) & 3, cn);
        }
        __builtin_amdgcn_sched_barrier(0);
        FMA2(A, 6);
        FMA2(B, 7);
    }

    // ---- epilogue: bias + nontemporal float2 stores (8B-aligned), 2 o's
#pragma unroll
    for (int oo = 0; oo < 2; ++oo) {
        const int oc = o0 + oo;
        const float* brow = bias + ((long)oc * OH_ + h) * OW_ + w0;
        float2 bv0 = *reinterpret_cast<const float2*>(brow);
        float2 bv1;
        if (full) bv1 = *reinterpret_cast<const float2*>(brow + 2);
        else { bv1.x = 0.f; bv1.y = 0.f; }
#pragma unroll
        for (int bi = 0; bi < 8; ++bi) {
            const float* a_ = oo ? acc1[bi] : acc0[bi];
            float* orow = out + (((long)(b0 + bi) * O_ + oc) * OH_ + h) * OW_ + w0;
            vfloat2 s0; s0.x = a_[0] + bv0.x; s0.y = a_[1] + bv0.y;
            __builtin_nontemporal_store(s0, reinterpret_cast<vfloat2*>(orow));
            if (full) {
                vfloat2 s1; s1.x = a_[2] + bv1.x; s1.y = a_[3] + bv1.y;
                __builtin_nontemporal_store(s1, reinterpret_cast<vfloat2*>(orow) + 1);
            }
        }
    }

#undef STAGE_W2
#undef DSREAD_W2
#undef WQ0
#undef WQ1
#undef XLD
#undef FMA2
}

extern "C" void kernel_launch(void* const* d_in, const int* in_sizes, int n_in,
                              void* d_out, int out_size, void* d_ws, size_t ws_size,
                              hipStream_t stream) {
    const float* x    = (const float*)d_in[0];
    const float* Wt   = (const float*)d_in[1];
    const float* bias = (const float*)d_in[2];
    float* out        = (float*)d_out;

    dim3 grid(8 * OH_);   // 496 blocks (8 o-octets x 62 h), XCD-swizzled
    dim3 block(256);
    lcl_kernel<<<grid, block, 0, stream>>>(x, Wt, bias, out);
}

// Round 15
// 159.195 us; speedup vs baseline: 1.7343x; 1.0068x over previous
//
#include <hip/hip_runtime.h>

// Locally connected layer:
// out[b,o,h,w] = sum_{c,i,j} x[b,c,h+i,w+j] * W[o,c,h,w,i,j] + bias[o,h,w]
// x: [32,32,64,64] f32, W: [64,32,62,62,3,3] f32, bias: [64,62,62] f32
// out: [32,64,62,62] f32
//
// R15 = R14 + __launch_bounds__(256, 2).
// R14 post-mortem: VGPR=116 < live-set demand (~190: acc 64 + wq 72 + xv 36
// + addr) -> compiler serialized wq through LDS re-reads; VALUBusy 25%.
// LDS (73.7 KB) already caps occupancy at 2 blocks/CU = 2 waves/SIMD, so
// min-waves=2 (VGPR cap 256) costs nothing and frees the allocator.
// Earlier spills (R4 cap 128, R8 cap 170) were caps BELOW demand; 256 > 190.
//
// Structure (validated R14): 2 o's/wave, barrier-free, W coalesced
// gll->LDS depth-3 prefetch over 4 buffers (top vmcnt(36) waits only on a
// gll issued 3 channels ago), x direct float4 3-slot rotation interleaved
// with FMAs, STAGE_W(c+3) youngest. DPP halo 0x101 (R8), chunked XCD
// swizzle (R3), nontemporal stores.

#define C_  32
#define B_  32
#define O_  64
#define H_  64
#define W_  64
#define OH_ 62
#define OW_ 62

typedef float vfloat2 __attribute__((ext_vector_type(2)));
typedef float vfloat4 __attribute__((ext_vector_type(4)));

#define GLL4(gaddr, laddr)                                                      \
    __builtin_amdgcn_global_load_lds(                                           \
        (const __attribute__((address_space(1))) void*)(gaddr),                 \
        (__attribute__((address_space(3))) void*)(laddr), 4, 0, 0)

// dst[lane] = src[lane+1] within each 16-lane row (validated R8)
__device__ __forceinline__ float dpp_nextlane(float v) {
    return __int_as_float(__builtin_amdgcn_update_dpp(
        0, __float_as_int(v), 0x101, 0xf, 0xf, true));
}

#define WAITV(n) do {                                                           \
        asm volatile("s_waitcnt vmcnt(" #n ")" ::: "memory");                   \
        __builtin_amdgcn_sched_barrier(0);                                      \
    } while (0)

__global__ __launch_bounds__(256, 2)
void lcl_kernel(const float* __restrict__ x,
                const float* __restrict__ Wt,
                const float* __restrict__ bias,
                float* __restrict__ out) {
    // W rows: [4 buffers][4 waves][2 o's][576 floats] = 73728 B
    __shared__ float ldsW[4][4][2][576];

    // ---- chunked XCD swizzle (hw: XCD = blockIdx.x % 8); 496 = 8 * 62
    const int i0      = blockIdx.x;
    const int logical = (i0 & 7) * 62 + (i0 >> 3);
    const int og      = logical & 7;                 // o-octet (fast)
    const int h       = logical >> 3;                // 0..61

    const int wv_i = threadIdx.x >> 6;               // wave 0..3
    const int o0   = (og << 3) + (wv_i << 1);        // this wave: o0, o0+1
    const int lane = threadIdx.x & 63;
    const int wg   = lane & 15;                      // w0 = 4*wg
    const int bg   = lane >> 4;                      // b0 = 8*bg
    const int w0   = wg * 4;
    const int b0   = bg * 8;
    const bool full = (wg < 15);                     // wg15 stores only w=60,61

    float acc0[8][4], acc1[8][4];
#pragma unroll
    for (int bi = 0; bi < 8; ++bi)
#pragma unroll
        for (int wi = 0; wi < 4; ++wi) { acc0[bi][wi] = 0.f; acc1[bi][wi] = 0.f; }

    // W row bases (floats): o*C*34596 + h*558
    const long wrow0 = (long)o0 * (C_ * 34596) + (long)h * 558;
    const long wrow1 = wrow0 + (long)C_ * 34596;     // o0+1

    // x byte base for (b0, h, w0)
    const char* xb0 = (const char*)x + (unsigned)b0 * 524288u
                      + (unsigned)h * 256u + (unsigned)wg * 16u;

    // stage both 2232-B W rows coalesced (2 x 9 gll dword; tail instr covers
    // [1976,2232), overlap [1976,2048) double-written with same data).
#define STAGE_W2(buf, cidx) do {                                                \
        const char* s0_ = (const char*)(Wt + wrow0 + (long)(cidx) * 34596);     \
        const char* s1_ = (const char*)(Wt + wrow1 + (long)(cidx) * 34596);     \
        char* d0_ = (char*)&ldsW[buf][wv_i][0][0];                              \
        char* d1_ = (char*)&ldsW[buf][wv_i][1][0];                              \
        _Pragma("unroll")                                                       \
        for (int k_ = 0; k_ < 8; ++k_)                                          \
            GLL4(s0_ + k_ * 256 + lane * 4, d0_ + k_ * 256);                    \
        GLL4(s0_ + 1976 + lane * 4, d0_ + 1976);                                \
        _Pragma("unroll")                                                       \
        for (int k_ = 0; k_ < 8; ++k_)                                          \
            GLL4(s1_ + k_ * 256 + lane * 4, d1_ + k_ * 256);                    \
        GLL4(s1_ + 1976 + lane * 4, d1_ + 1976);                                \
    } while (0)

    // lane's 36 W floats per o (9 ds_read_b128, 144-B lane stride = 2-way
    // alias = free). wg=15 tail reads pad garbage, never stored.
#define DSREAD_W2(buf) do {                                                     \
        const char* r0_ = (const char*)&ldsW[buf][wv_i][0][0] + wg * 144;       \
        const char* r1_ = (const char*)&ldsW[buf][wv_i][1][0] + wg * 144;       \
        _Pragma("unroll")                                                       \
        for (int q_ = 0; q_ < 9; ++q_) {                                        \
            wq0[q_] = *reinterpret_cast<const vfloat4*>(r0_ + q_ * 16);         \
            wq1[q_] = *reinterpret_cast<const vfloat4*>(r1_ + q_ * 16);         \
        }                                                                       \
    } while (0)

#define WQ0(t) (wq0[(t) >> 2][(t) & 3])
#define WQ1(t) (wq1[(t) >> 2][(t) & 3])

    // issue 3 float4 rows of batch b0+bi_ for channel cidx into slot s_
#define XLD(s_, cidx, bi_) do {                                                 \
        const char* p_ = xb0 + (unsigned)(bi_) * 524288u                        \
                         + (unsigned)(cidx) * 16384u;                           \
        xv##s_[0] = *reinterpret_cast<const float4*>(p_);                       \
        xv##s_[1] = *reinterpret_cast<const float4*>(p_ + 256);                 \
        xv##s_[2] = *reinterpret_cast<const float4*>(p_ + 512);                 \
    } while (0)

    // expand slot s_ via DPP halo, 36 FMAs into acc0[bi_] + 36 into acc1[bi_]
#define FMA2(s_, bi_) do {                                                      \
        float xr_[3][6];                                                        \
        _Pragma("unroll")                                                       \
        for (int r_ = 0; r_ < 3; ++r_) {                                        \
            xr_[r_][0] = xv##s_[r_].x; xr_[r_][1] = xv##s_[r_].y;               \
            xr_[r_][2] = xv##s_[r_].z; xr_[r_][3] = xv##s_[r_].w;               \
            xr_[r_][4] = dpp_nextlane(xv##s_[r_].x);                            \
            xr_[r_][5] = dpp_nextlane(xv##s_[r_].y);                            \
        }                                                                       \
        _Pragma("unroll")                                                       \
        for (int wi_ = 0; wi_ < 4; ++wi_)                                       \
        _Pragma("unroll")                                                       \
        for (int ii_ = 0; ii_ < 3; ++ii_)                                       \
        _Pragma("unroll")                                                       \
        for (int j_ = 0; j_ < 3; ++j_) {                                        \
            acc0[bi_][wi_] = fmaf(xr_[ii_][wi_ + j_],                           \
                                  WQ0(wi_ * 9 + ii_ * 3 + j_), acc0[bi_][wi_]); \
            acc1[bi_][wi_] = fmaf(xr_[ii_][wi_ + j_],                           \
                                  WQ1(wi_ * 9 + ii_ * 3 + j_), acc1[bi_][wi_]); \
        }                                                                       \
    } while (0)

    vfloat4 wq0[9], wq1[9];
    float4  xvA[3], xvB[3], xvC[3];

    // ---- prologue: depth-3 W prefetch (54 gll outstanding)
    STAGE_W2(0, 0);
    STAGE_W2(1, 1);
    STAGE_W2(2, 2);

    for (int c = 0; c < C_; ++c) {
        // gll(c) landed iff <= 36 outstanding (gll(c+1), gll(c+2) may remain;
        // gll(c) itself was issued 3 channels ago -> wait is ~free).
        WAITV(36);
        DSREAD_W2(c & 3);                 // 18 ds_read_b128 (compiler lgkm)
        XLD(A, c, 0);
        XLD(B, c, 1);
        __builtin_amdgcn_sched_barrier(0);
        XLD(C, c, 2); FMA2(A, 0);
        XLD(A, c, 3); FMA2(B, 1);
        XLD(B, c, 4); FMA2(C, 2);
        XLD(C, c, 5); FMA2(A, 3);
        XLD(A, c, 6); FMA2(B, 4);
        XLD(B, c, 7); FMA2(C, 5);
        __builtin_amdgcn_sched_barrier(0);
        {                                 // stage W(c+3): YOUNGEST VMEM
            const int cn = (c + 3 < C_) ? (c + 3) : (C_ - 1);
            STAGE_W2((c + 3) & 3, cn);
        }
        __builtin_amdgcn_sched_barrier(0);
        FMA2(A, 6);
        FMA2(B, 7);
    }

    // ---- epilogue: bias + nontemporal float2 stores (8B-aligned), 2 o's
#pragma unroll
    for (int oo = 0; oo < 2; ++oo) {
        const int oc = o0 + oo;
        const float* brow = bias + ((long)oc * OH_ + h) * OW_ + w0;
        float2 bv0 = *reinterpret_cast<const float2*>(brow);
        float2 bv1;
        if (full) bv1 = *reinterpret_cast<const float2*>(brow + 2);
        else { bv1.x = 0.f; bv1.y = 0.f; }
#pragma unroll
        for (int bi = 0; bi < 8; ++bi) {
            const float* a_ = oo ? acc1[bi] : acc0[bi];
            float* orow = out + (((long)(b0 + bi) * O_ + oc) * OH_ + h) * OW_ + w0;
            vfloat2 s0; s0.x = a_[0] + bv0.x; s0.y = a_[1] + bv0.y;
            __builtin_nontemporal_store(s0, reinterpret_cast<vfloat2*>(orow));
            if (full) {
                vfloat2 s1; s1.x = a_[2] + bv1.x; s1.y = a_[3] + bv1.y;
                __builtin_nontemporal_store(s1, reinterpret_cast<vfloat2*>(orow) + 1);
            }
        }
    }

#undef STAGE_W2
#undef DSREAD_W2
#undef WQ0
#undef WQ1
#undef XLD
#undef FMA2
}

extern "C" void kernel_launch(void* const* d_in, const int* in_sizes, int n_in,
                              void* d_out, int out_size, void* d_ws, size_t ws_size,
                              hipStream_t stream) {
    const float* x    = (const float*)d_in[0];
    const float* Wt   = (const float*)d_in[1];
    const float* bias = (const float*)d_in[2];
    float* out        = (float*)d_out;

    dim3 grid(8 * OH_);   // 496 blocks (8 o-octets x 62 h), XCD-swizzled
    dim3 block(256);
    lcl_kernel<<<grid, block, 0, stream>>>(x, Wt, bias, out);
}

// Round 16
// 157.750 us; speedup vs baseline: 1.7502x; 1.0092x over previous
//
#include <hip/hip_runtime.h>

// Locally connected layer:
// out[b,o,h,w] = sum_{c,i,j} x[b,c,h+i,w+j] * W[o,c,h,w,i,j] + bias[o,h,w]
// x: [32,32,64,64] f32, W: [64,32,62,62,3,3] f32, bias: [64,62,62] f32
// out: [32,64,62,62] f32
//
// R16 = R14 structure with W prefetch depth-2 over 2 LDS buffers.
// R15 post-mortem: no pipe is saturated (L1 ~3.1K cy, LDS ~1.7K cy, FMA
// ~2.5K cy per CU-channel vs 15.6K elapsed) -> latency-stall at 2 waves/SIMD.
// LDS was the occupancy limiter (73.7 KB). Depth-2/2-buffer W staging halves
// LDS to 36.9 KB -> 4 blocks/CU = 4 waves/SIMD, doubling stall cover.
// FIFO stays clean: top WAITV(18) waits only for gll(c) (issued 2 channels
// ago); gll(c+1) (1 channel old) rides across the channel. Buffer reuse is
// per-wave-private and program-ordered (ds_reads precede the re-stage).
//
// Validated pieces: 2 o's/wave, coalesced W gll->LDS (R10), barrier-free
// (R12), x 3-slot float4 rotation interleaved with FMAs, STAGE_W youngest,
// DPP halo 0x101 (R8), chunked XCD swizzle (R3), nontemporal stores.

#define C_  32
#define B_  32
#define O_  64
#define H_  64
#define W_  64
#define OH_ 62
#define OW_ 62

typedef float vfloat2 __attribute__((ext_vector_type(2)));
typedef float vfloat4 __attribute__((ext_vector_type(4)));

#define GLL4(gaddr, laddr)                                                      \
    __builtin_amdgcn_global_load_lds(                                           \
        (const __attribute__((address_space(1))) void*)(gaddr),                 \
        (__attribute__((address_space(3))) void*)(laddr), 4, 0, 0)

// dst[lane] = src[lane+1] within each 16-lane row (validated R8)
__device__ __forceinline__ float dpp_nextlane(float v) {
    return __int_as_float(__builtin_amdgcn_update_dpp(
        0, __float_as_int(v), 0x101, 0xf, 0xf, true));
}

#define WAITV(n) do {                                                           \
        asm volatile("s_waitcnt vmcnt(" #n ")" ::: "memory");                   \
        __builtin_amdgcn_sched_barrier(0);                                      \
    } while (0)

__global__ __launch_bounds__(256)
void lcl_kernel(const float* __restrict__ x,
                const float* __restrict__ Wt,
                const float* __restrict__ bias,
                float* __restrict__ out) {
    // W rows: [2 buffers][4 waves][2 o's][576 floats] = 36864 B -> 4 blk/CU
    __shared__ float ldsW[2][4][2][576];

    // ---- chunked XCD swizzle (hw: XCD = blockIdx.x % 8); 496 = 8 * 62
    const int i0      = blockIdx.x;
    const int logical = (i0 & 7) * 62 + (i0 >> 3);
    const int og      = logical & 7;                 // o-octet (fast)
    const int h       = logical >> 3;                // 0..61

    const int wv_i = threadIdx.x >> 6;               // wave 0..3
    const int o0   = (og << 3) + (wv_i << 1);        // this wave: o0, o0+1
    const int lane = threadIdx.x & 63;
    const int wg   = lane & 15;                      // w0 = 4*wg
    const int bg   = lane >> 4;                      // b0 = 8*bg
    const int w0   = wg * 4;
    const int b0   = bg * 8;
    const bool full = (wg < 15);                     // wg15 stores only w=60,61

    float acc0[8][4], acc1[8][4];
#pragma unroll
    for (int bi = 0; bi < 8; ++bi)
#pragma unroll
        for (int wi = 0; wi < 4; ++wi) { acc0[bi][wi] = 0.f; acc1[bi][wi] = 0.f; }

    // W row bases (floats): o*C*34596 + h*558
    const long wrow0 = (long)o0 * (C_ * 34596) + (long)h * 558;
    const long wrow1 = wrow0 + (long)C_ * 34596;     // o0+1

    // x byte base for (b0, h, w0)
    const char* xb0 = (const char*)x + (unsigned)b0 * 524288u
                      + (unsigned)h * 256u + (unsigned)wg * 16u;

    // stage both 2232-B W rows coalesced (2 x 9 gll dword; tail instr covers
    // [1976,2232), overlap [1976,2048) double-written with same data).
#define STAGE_W2(buf, cidx) do {                                                \
        const char* s0_ = (const char*)(Wt + wrow0 + (long)(cidx) * 34596);     \
        const char* s1_ = (const char*)(Wt + wrow1 + (long)(cidx) * 34596);     \
        char* d0_ = (char*)&ldsW[buf][wv_i][0][0];                              \
        char* d1_ = (char*)&ldsW[buf][wv_i][1][0];                              \
        _Pragma("unroll")                                                       \
        for (int k_ = 0; k_ < 8; ++k_)                                          \
            GLL4(s0_ + k_ * 256 + lane * 4, d0_ + k_ * 256);                    \
        GLL4(s0_ + 1976 + lane * 4, d0_ + 1976);                                \
        _Pragma("unroll")                                                       \
        for (int k_ = 0; k_ < 8; ++k_)                                          \
            GLL4(s1_ + k_ * 256 + lane * 4, d1_ + k_ * 256);                    \
        GLL4(s1_ + 1976 + lane * 4, d1_ + 1976);                                \
    } while (0)

    // lane's 36 W floats per o (9 ds_read_b128, 144-B lane stride = 2-way
    // alias = free). wg=15 tail reads pad garbage, never stored.
#define DSREAD_W2(buf) do {                                                     \
        const char* r0_ = (const char*)&ldsW[buf][wv_i][0][0] + wg * 144;       \
        const char* r1_ = (const char*)&ldsW[buf][wv_i][1][0] + wg * 144;       \
        _Pragma("unroll")                                                       \
        for (int q_ = 0; q_ < 9; ++q_) {                                        \
            wq0[q_] = *reinterpret_cast<const vfloat4*>(r0_ + q_ * 16);         \
            wq1[q_] = *reinterpret_cast<const vfloat4*>(r1_ + q_ * 16);         \
        }                                                                       \
    } while (0)

#define WQ0(t) (wq0[(t) >> 2][(t) & 3])
#define WQ1(t) (wq1[(t) >> 2][(t) & 3])

    // issue 3 float4 rows of batch b0+bi_ for channel cidx into slot s_
#define XLD(s_, cidx, bi_) do {                                                 \
        const char* p_ = xb0 + (unsigned)(bi_) * 524288u                        \
                         + (unsigned)(cidx) * 16384u;                           \
        xv##s_[0] = *reinterpret_cast<const float4*>(p_);                       \
        xv##s_[1] = *reinterpret_cast<const float4*>(p_ + 256);                 \
        xv##s_[2] = *reinterpret_cast<const float4*>(p_ + 512);                 \
    } while (0)

    // expand slot s_ via DPP halo, 36 FMAs into acc0[bi_] + 36 into acc1[bi_]
#define FMA2(s_, bi_) do {                                                      \
        float xr_[3][6];                                                        \
        _Pragma("unroll")                                                       \
        for (int r_ = 0; r_ < 3; ++r_) {                                        \
            xr_[r_][0] = xv##s_[r_].x; xr_[r_][1] = xv##s_[r_].y;               \
            xr_[r_][2] = xv##s_[r_].z; xr_[r_][3] = xv##s_[r_].w;               \
            xr_[r_][4] = dpp_nextlane(xv##s_[r_].x);                            \
            xr_[r_][5] = dpp_nextlane(xv##s_[r_].y);                            \
        }                                                                       \
        _Pragma("unroll")                                                       \
        for (int wi_ = 0; wi_ < 4; ++wi_)                                       \
        _Pragma("unroll")                                                       \
        for (int ii_ = 0; ii_ < 3; ++ii_)                                       \
        _Pragma("unroll")                                                       \
        for (int j_ = 0; j_ < 3; ++j_) {                                        \
            acc0[bi_][wi_] = fmaf(xr_[ii_][wi_ + j_],                           \
                                  WQ0(wi_ * 9 + ii_ * 3 + j_), acc0[bi_][wi_]); \
            acc1[bi_][wi_] = fmaf(xr_[ii_][wi_ + j_],                           \
                                  WQ1(wi_ * 9 + ii_ * 3 + j_), acc1[bi_][wi_]); \
        }                                                                       \
    } while (0)

    vfloat4 wq0[9], wq1[9];
    float4  xvA[3], xvB[3], xvC[3];

    // ---- prologue: depth-2 W prefetch (36 gll outstanding)
    STAGE_W2(0, 0);
    STAGE_W2(1, 1);

    for (int c = 0; c < C_; ++c) {
        // gll(c) landed iff <= 18 outstanding (only gll(c+1), issued one
        // channel ago, may remain).
        WAITV(18);
        DSREAD_W2(c & 1);                 // 18 ds_read_b128 (compiler lgkm)
        XLD(A, c, 0);
        XLD(B, c, 1);
        __builtin_amdgcn_sched_barrier(0);
        XLD(C, c, 2); FMA2(A, 0);
        XLD(A, c, 3); FMA2(B, 1);
        XLD(B, c, 4); FMA2(C, 2);
        XLD(C, c, 5); FMA2(A, 3);
        XLD(A, c, 6); FMA2(B, 4);
        XLD(B, c, 7); FMA2(C, 5);
        __builtin_amdgcn_sched_barrier(0);
        {                                 // stage W(c+2): YOUNGEST VMEM.
            // Writes buf c&1 (read at top of THIS channel by this wave;
            // program order makes that safe - per-wave private LDS slots).
            const int cn = (c + 2 < C_) ? (c + 2) : (C_ - 1);
            STAGE_W2((c + 2) & 1, cn);
        }
        __builtin_amdgcn_sched_barrier(0);
        FMA2(A, 6);
        FMA2(B, 7);
    }

    // ---- epilogue: bias + nontemporal float2 stores (8B-aligned), 2 o's
#pragma unroll
    for (int oo = 0; oo < 2; ++oo) {
        const int oc = o0 + oo;
        const float* brow = bias + ((long)oc * OH_ + h) * OW_ + w0;
        float2 bv0 = *reinterpret_cast<const float2*>(brow);
        float2 bv1;
        if (full) bv1 = *reinterpret_cast<const float2*>(brow + 2);
        else { bv1.x = 0.f; bv1.y = 0.f; }
#pragma unroll
        for (int bi = 0; bi < 8; ++bi) {
            const float* a_ = oo ? acc1[bi] : acc0[bi];
            float* orow = out + (((long)(b0 + bi) * O_ + oc) * OH_ + h) * OW_ + w0;
            vfloat2 s0; s0.x = a_[0] + bv0.x; s0.y = a_[1] + bv0.y;
            __builtin_nontemporal_store(s0, reinterpret_cast<vfloat2*>(orow));
            if (full) {
                vfloat2 s1; s1.x = a_[2] + bv1.x; s1.y = a_[3] + bv1.y;
                __builtin_nontemporal_store(s1, reinterpret_cast<vfloat2*>(orow) + 1);
            }
        }
    }

#undef STAGE_W2
#undef DSREAD_W2
#undef WQ0
#undef WQ1
#undef XLD
#undef FMA2
}

extern "C" void kernel_launch(void* const* d_in, const int* in_sizes, int n_in,
                              void* d_out, int out_size, void* d_ws, size_t ws_size,
                              hipStream_t stream) {
    const float* x    = (const float*)d_in[0];
    const float* Wt   = (const float*)d_in[1];
    const float* bias = (const float*)d_in[2];
    float* out        = (float*)d_out;

    dim3 grid(8 * OH_);   // 496 blocks (8 o-octets x 62 h), XCD-swizzled
    dim3 block(256);
    lcl_kernel<<<grid, block, 0, stream>>>(x, Wt, bias, out);
}